// Round 3
// baseline (1956.847 us; speedup 1.0000x reference)
//
#include <hip/hip_runtime.h>

#define BB 8
#define SS 4096
#define HH 2048
#define EE 32
#define FF 128

constexpr size_t DELTA_N = (size_t)BB * SS * HH;  // 67108864

__device__ __forceinline__ unsigned short f2bfu(float x) {
  unsigned int u = __float_as_uint(x);
  u = (u + 0x7FFFu + ((u >> 16) & 1u)) >> 16;  // RNE
  return (unsigned short)u;
}
__device__ __forceinline__ float bfu2f(unsigned short u) {
  return __uint_as_float(((unsigned int)u) << 16);
}

// ---------------- ws float layout ----------------
// [0..255]   logits (atomicAdd accumulators)
// [256..271] sel (int)
// [272..287] pscale (float)

__global__ void k_zero(float* __restrict__ ws) {
  if (threadIdx.x < 288) ws[threadIdx.x] = 0.0f;
}

// grid BB*32 (= b*32 + hc), block 256.
__global__ void k_pool_logits(const float* __restrict__ hidden,
                              const float* __restrict__ rw,
                              float* __restrict__ logits) {
  const int b  = blockIdx.x >> 5;
  const int hc = blockIdx.x & 31;
  const int t  = threadIdx.x;
  const int col = t & 63;
  const int qq  = t >> 6;
  const int h = hc * 64 + col;

  const float* p = hidden + ((size_t)b * SS + (size_t)qq * 1024) * HH + h;
  float a0 = 0.f, a1 = 0.f, a2 = 0.f, a3 = 0.f;
  for (int s = 0; s < 1024; s += 4) {
    a0 += p[(size_t)(s + 0) * HH];
    a1 += p[(size_t)(s + 1) * HH];
    a2 += p[(size_t)(s + 2) * HH];
    a3 += p[(size_t)(s + 3) * HH];
  }
  __shared__ float ps[4][64];
  __shared__ float pl[64];
  ps[qq][col] = a0 + a1 + a2 + a3;
  __syncthreads();
  if (t < 64) pl[t] = (ps[0][t] + ps[1][t] + ps[2][t] + ps[3][t]) * (1.0f / (float)SS);
  __syncthreads();

  const int e = t >> 3, part = t & 7;
  const float* wr = rw + (size_t)e * HH + hc * 64 + part * 8;
  float v = 0.f;
#pragma unroll
  for (int m = 0; m < 8; ++m) v += pl[part * 8 + m] * wr[m];
  v += __shfl_xor(v, 1, 8);
  v += __shfl_xor(v, 2, 8);
  v += __shfl_xor(v, 4, 8);
  if (part == 0) atomicAdd(&logits[b * EE + e], v);
}

// grid 1, block 256 (t = b*32+e). All outputs written as FLOAT32.
__global__ void k_topk(const float* __restrict__ logits, const float* __restrict__ rb,
                       const float* __restrict__ counts, const float* __restrict__ drift,
                       int* __restrict__ sel, float* __restrict__ pscale,
                       float* __restrict__ out) {
  int t = threadIdx.x;
  int b = t >> 5, e = t & 31;
  float total = 0.0f, cmax = 0.0f, dmax = 0.0f;
  for (int i = 0; i < EE; ++i) {
    float c = counts[i]; total += c; cmax = fmaxf(cmax, c);
    float d = drift[i];  dmax = fmaxf(dmax, d);
  }
  float cnt = counts[e], dr = drift[e];
  float usage = cnt / fmaxf(total, 1e-8f);
  float bonus = (total > 0.0f) ? 0.1f * (1.0f - usage) : 0.0f;
  float un = cnt / fmaxf(cmax, 1e-8f);
  float dn = dr / fmaxf(dmax, 1e-8f);
  float l = logits[t] + rb[e] + bonus - 0.05f * (un + dn);

  float m = l;
  for (int w = 16; w; w >>= 1) m = fmaxf(m, __shfl_xor(m, w, 32));
  float p = expf(l - m);
  float ssum = p;
  for (int w = 16; w; w >>= 1) ssum += __shfl_xor(ssum, w, 32);
  float prob = p / ssum;
  out[DELTA_N + 32 + t] = prob;  // router_probs[b][e]

  // top-1 (greater value wins; tie -> lower index)
  float v1 = prob; int i1 = e;
  for (int w = 16; w; w >>= 1) {
    float ov = __shfl_xor(v1, w, 32); int oi = __shfl_xor(i1, w, 32);
    if (ov > v1 || (ov == v1 && oi < i1)) { v1 = ov; i1 = oi; }
  }
  // top-2 (exclude i1)
  float v2 = (e == i1) ? -1.0f : prob; int i2 = e;
  for (int w = 16; w; w >>= 1) {
    float ov = __shfl_xor(v2, w, 32); int oi = __shfl_xor(i2, w, 32);
    if (ov > v2 || (ov == v2 && oi < i2)) { v2 = ov; i2 = oi; }
  }
  if (e == 0) {
    float denom = fmaxf(v1 + v2, 1e-8f);
    float tp0 = v1 / denom, tp1 = v2 / denom;
    sel[b * 2 + 0] = i1;
    sel[b * 2 + 1] = i2;
    pscale[b * 2 + 0] = tp0;
    pscale[b * 2 + 1] = tp1;
    out[DELTA_N + 0 + b * 2 + 0] = (float)i1;
    out[DELTA_N + 0 + b * 2 + 1] = (float)i2;
    out[DELTA_N + 16 + b * 2 + 0] = tp0;
    out[DELTA_N + 16 + b * 2 + 1] = tp1;
  }
}

// ---------------- fused expert FFN ----------------
// grid (SS/64, BB), block 256. Rows [s0,s0+64). u=t&31, g=t>>5.
// Output ownership: rows r=g*8+i, cols c=u+32*j.
__global__ __launch_bounds__(256, 1) void k_ffn(
    const float* __restrict__ hidden, const float* __restrict__ w1,
    const float* __restrict__ b1, const float* __restrict__ w2,
    const float* __restrict__ b2, const int* __restrict__ sel,
    const float* __restrict__ pscale, float* __restrict__ out) {
  __shared__ float sA[64][17];            // hidden rows x k-chunk
  __shared__ float sB[16][257];           // k x 256 cols (w1cat, then w2cat)
  __shared__ unsigned short sG[64][257];  // p * gelu(h1), bf16

  const int b  = blockIdx.y;
  const int s0 = blockIdx.x * 64;
  const int t  = threadIdx.x;
  const int u  = t & 31;
  const int g  = t >> 5;

  const int e0 = sel[2 * b], e1 = sel[2 * b + 1];
  const float p0 = pscale[2 * b], p1 = pscale[2 * b + 1];

  float acc[8][8];
#pragma unroll
  for (int i = 0; i < 8; ++i)
#pragma unroll
    for (int j = 0; j < 8; ++j) acc[i][j] = 0.0f;

  // ---- GEMM1: g1[r][c] = sum_h hidden[b][s0+r][h] * w1cat[c][h]
  const int   et1  = (t < 128) ? e0 : e1;
  const float* wrow = w1 + ((size_t)et1 * FF + (t & 127)) * HH;
  const float* hrow = hidden + ((size_t)b * SS + s0) * HH;

  for (int k0 = 0; k0 < HH; k0 += 16) {
    {
      const int r = t >> 2, kq = (t & 3) * 4;
      float4 v = *(const float4*)(hrow + (size_t)r * HH + k0 + kq);
      sA[r][kq + 0] = v.x; sA[r][kq + 1] = v.y;
      sA[r][kq + 2] = v.z; sA[r][kq + 3] = v.w;
    }
    {
#pragma unroll
      for (int q = 0; q < 4; ++q) {
        float4 v = *(const float4*)(wrow + k0 + q * 4);
        sB[q * 4 + 0][t] = v.x; sB[q * 4 + 1][t] = v.y;
        sB[q * 4 + 2][t] = v.z; sB[q * 4 + 3][t] = v.w;
      }
    }
    __syncthreads();
#pragma unroll
    for (int kk = 0; kk < 16; ++kk) {
      float ai[8], bj[8];
#pragma unroll
      for (int i = 0; i < 8; ++i) ai[i] = sA[g * 8 + i][kk];
#pragma unroll
      for (int j = 0; j < 8; ++j) bj[j] = sB[kk][u + 32 * j];
#pragma unroll
      for (int i = 0; i < 8; ++i)
#pragma unroll
        for (int j = 0; j < 8; ++j) acc[i][j] = fmaf(ai[i], bj[j], acc[i][j]);
    }
    __syncthreads();
  }

  // ---- epilogue 1: bias + exact gelu + prob scale -> sG (bf16)
#pragma unroll
  for (int j = 0; j < 8; ++j) {
    const int c = u + 32 * j;
    const int ec = (c < 128) ? e0 : e1;
    const float pc = (c < 128) ? p0 : p1;
    const float bias = b1[ec * FF + (c & 127)];
#pragma unroll
    for (int i = 0; i < 8; ++i) {
      float x = acc[i][j] + bias;
      float gl = 0.5f * x * (1.0f + erff(x * 0.70710678118654752f));
      sG[g * 8 + i][c] = f2bfu(pc * gl);
    }
  }
  __syncthreads();

  // ---- GEMM2: delta[r][h] = sum_{c=0..255} g1[r][c] * w2cat[h][c]
  for (int n0 = 0; n0 < HH; n0 += 256) {
#pragma unroll
    for (int i = 0; i < 8; ++i)
#pragma unroll
      for (int j = 0; j < 8; ++j) acc[i][j] = 0.0f;

    for (int kf0 = 0; kf0 < 256; kf0 += 16) {
      const int et2 = (kf0 < 128) ? e0 : e1;
      const int fb  = kf0 & 127;
      const float* w2row = w2 + ((size_t)et2 * HH + (n0 + t)) * FF + fb;
#pragma unroll
      for (int q = 0; q < 4; ++q) {
        float4 v = *(const float4*)(w2row + q * 4);
        sB[q * 4 + 0][t] = v.x; sB[q * 4 + 1][t] = v.y;
        sB[q * 4 + 2][t] = v.z; sB[q * 4 + 3][t] = v.w;
      }
      __syncthreads();
#pragma unroll
      for (int kk = 0; kk < 16; ++kk) {
        float ai[8], bj[8];
#pragma unroll
        for (int i = 0; i < 8; ++i) ai[i] = bfu2f(sG[g * 8 + i][kf0 + kk]);
#pragma unroll
        for (int j = 0; j < 8; ++j) bj[j] = sB[kk][u + 32 * j];
#pragma unroll
        for (int i = 0; i < 8; ++i)
#pragma unroll
          for (int j = 0; j < 8; ++j) acc[i][j] = fmaf(ai[i], bj[j], acc[i][j]);
      }
      __syncthreads();
    }

#pragma unroll
    for (int j = 0; j < 8; ++j) {
      const int h = n0 + u + 32 * j;
      const float bias = p0 * b2[(size_t)e0 * HH + h] + p1 * b2[(size_t)e1 * HH + h];
#pragma unroll
      for (int i = 0; i < 8; ++i) {
        size_t idx = ((size_t)b * SS + s0 + g * 8 + i) * HH + h;
        out[idx] = acc[i][j] + bias;
      }
    }
  }
}

extern "C" void kernel_launch(void* const* d_in, const int* in_sizes, int n_in,
                              void* d_out, int out_size, void* d_ws, size_t ws_size,
                              hipStream_t stream) {
  const float* hidden   = (const float*)d_in[0];
  const float* router_w = (const float*)d_in[1];
  const float* router_b = (const float*)d_in[2];
  const float* w1       = (const float*)d_in[3];
  const float* b1       = (const float*)d_in[4];
  const float* w2       = (const float*)d_in[5];
  const float* b2       = (const float*)d_in[6];
  const float* counts   = (const float*)d_in[7];
  const float* drift    = (const float*)d_in[8];
  float* out            = (float*)d_out;

  float* logits = (float*)d_ws;          // 256 floats
  int*   sel    = (int*)(logits + 256);  // 16 ints
  float* pscale = logits + 272;          // 16 floats

  k_zero<<<1, 288, 0, stream>>>(logits);
  k_pool_logits<<<BB * 32, 256, 0, stream>>>(hidden, router_w, logits);
  k_topk<<<1, 256, 0, stream>>>(logits, router_b, counts, drift, sel, pscale, out);
  dim3 g3(SS / 64, BB);
  k_ffn<<<g3, 256, 0, stream>>>(hidden, w1, b1, w2, b2, sel, pscale, out);
}

// Round 4
// 559.618 us; speedup vs baseline: 3.4968x; 3.4968x over previous
//
#include <hip/hip_runtime.h>
#include <hip/hip_bf16.h>

#define BB 8
#define SS 4096
#define HH 2048
#define EE 32
#define FF 128

constexpr size_t DELTA_N = (size_t)BB * SS * HH;  // 67108864

typedef short bf16x8 __attribute__((ext_vector_type(8)));
typedef float f32x4 __attribute__((ext_vector_type(4)));
typedef unsigned short u16;

__device__ __forceinline__ u16 f2bfu(float x) {
  unsigned int u = __float_as_uint(x);
  u = (u + 0x7FFFu + ((u >> 16) & 1u)) >> 16;  // RNE
  return (u16)u;
}

__device__ __forceinline__ unsigned int pk2(float a, float b) {
  union { __hip_bfloat162 h; unsigned int u; } c;
  c.h = __float22bfloat162_rn(make_float2(a, b));
  return c.u;  // low 16 = a, high 16 = b
}

__device__ __forceinline__ bf16x8 pack8(float4 a, float4 b) {
  union { bf16x8 v; unsigned int u[4]; } r;
  r.u[0] = pk2(a.x, a.y);
  r.u[1] = pk2(a.z, a.w);
  r.u[2] = pk2(b.x, b.y);
  r.u[3] = pk2(b.z, b.w);
  return r.v;
}

// ---------------- router (unchanged, passes) ----------------
__global__ void k_zero(float* __restrict__ ws) {
  if (threadIdx.x < 288) ws[threadIdx.x] = 0.0f;
}

__global__ void k_pool_logits(const float* __restrict__ hidden,
                              const float* __restrict__ rw,
                              float* __restrict__ logits) {
  const int b  = blockIdx.x >> 5;
  const int hc = blockIdx.x & 31;
  const int t  = threadIdx.x;
  const int col = t & 63;
  const int qq  = t >> 6;
  const int h = hc * 64 + col;

  const float* p = hidden + ((size_t)b * SS + (size_t)qq * 1024) * HH + h;
  float a0 = 0.f, a1 = 0.f, a2 = 0.f, a3 = 0.f;
  for (int s = 0; s < 1024; s += 4) {
    a0 += p[(size_t)(s + 0) * HH];
    a1 += p[(size_t)(s + 1) * HH];
    a2 += p[(size_t)(s + 2) * HH];
    a3 += p[(size_t)(s + 3) * HH];
  }
  __shared__ float ps[4][64];
  __shared__ float pl[64];
  ps[qq][col] = a0 + a1 + a2 + a3;
  __syncthreads();
  if (t < 64) pl[t] = (ps[0][t] + ps[1][t] + ps[2][t] + ps[3][t]) * (1.0f / (float)SS);
  __syncthreads();

  const int e = t >> 3, part = t & 7;
  const float* wr = rw + (size_t)e * HH + hc * 64 + part * 8;
  float v = 0.f;
#pragma unroll
  for (int m = 0; m < 8; ++m) v += pl[part * 8 + m] * wr[m];
  v += __shfl_xor(v, 1, 8);
  v += __shfl_xor(v, 2, 8);
  v += __shfl_xor(v, 4, 8);
  if (part == 0) atomicAdd(&logits[b * EE + e], v);
}

__global__ void k_topk(const float* __restrict__ logits, const float* __restrict__ rb,
                       const float* __restrict__ counts, const float* __restrict__ drift,
                       int* __restrict__ sel, float* __restrict__ pscale,
                       float* __restrict__ out) {
  int t = threadIdx.x;
  int b = t >> 5, e = t & 31;
  float total = 0.0f, cmax = 0.0f, dmax = 0.0f;
  for (int i = 0; i < EE; ++i) {
    float c = counts[i]; total += c; cmax = fmaxf(cmax, c);
    float d = drift[i];  dmax = fmaxf(dmax, d);
  }
  float cnt = counts[e], dr = drift[e];
  float usage = cnt / fmaxf(total, 1e-8f);
  float bonus = (total > 0.0f) ? 0.1f * (1.0f - usage) : 0.0f;
  float un = cnt / fmaxf(cmax, 1e-8f);
  float dn = dr / fmaxf(dmax, 1e-8f);
  float l = logits[t] + rb[e] + bonus - 0.05f * (un + dn);

  float m = l;
  for (int w = 16; w; w >>= 1) m = fmaxf(m, __shfl_xor(m, w, 32));
  float p = expf(l - m);
  float ssum = p;
  for (int w = 16; w; w >>= 1) ssum += __shfl_xor(ssum, w, 32);
  float prob = p / ssum;
  out[DELTA_N + 32 + t] = prob;

  float v1 = prob; int i1 = e;
  for (int w = 16; w; w >>= 1) {
    float ov = __shfl_xor(v1, w, 32); int oi = __shfl_xor(i1, w, 32);
    if (ov > v1 || (ov == v1 && oi < i1)) { v1 = ov; i1 = oi; }
  }
  float v2 = (e == i1) ? -1.0f : prob; int i2 = e;
  for (int w = 16; w; w >>= 1) {
    float ov = __shfl_xor(v2, w, 32); int oi = __shfl_xor(i2, w, 32);
    if (ov > v2 || (ov == v2 && oi < i2)) { v2 = ov; i2 = oi; }
  }
  if (e == 0) {
    float denom = fmaxf(v1 + v2, 1e-8f);
    float tp0 = v1 / denom, tp1 = v2 / denom;
    sel[b * 2 + 0] = i1;
    sel[b * 2 + 1] = i2;
    pscale[b * 2 + 0] = tp0;
    pscale[b * 2 + 1] = tp1;
    out[DELTA_N + 0 + b * 2 + 0] = (float)i1;
    out[DELTA_N + 0 + b * 2 + 1] = (float)i2;
    out[DELTA_N + 16 + b * 2 + 0] = tp0;
    out[DELTA_N + 16 + b * 2 + 1] = tp1;
  }
}

// ---------------- MFMA fused expert FFN ----------------
// 1D grid 256 blocks: b = bid&7 (XCD swizzle), stile = bid>>3, s0 = stile*128.
// 512 threads = 8 waves; wave grid 2(row) x 4(col).
// GEMM1: M=128, N=256(w1cat), K=2048. GEMM2: M=128, N=2048, K=256.
__global__ __launch_bounds__(512, 2) void k_ffn(
    const float* __restrict__ hidden, const float* __restrict__ w1,
    const float* __restrict__ b1, const float* __restrict__ w2,
    const float* __restrict__ b2, const int* __restrict__ sel,
    const float* __restrict__ pscale, float* __restrict__ out) {
  __shared__ unsigned char sA[2][128 * 128];  // [buf][row*128B + (kbyte ^ swz(row))]
  __shared__ unsigned char sG[128 * 512];     // row*512B + (cbyte ^ swz(row))

  const int t    = threadIdx.x;
  const int lane = t & 63;
  const int wv   = t >> 6;   // 0..7
  const int wr   = wv >> 2;  // 0..1
  const int wc   = wv & 3;   // 0..3
  const int l15  = lane & 15;
  const int lk   = lane >> 4;  // 0..3

  const int bid = blockIdx.x;
  const int b   = bid & 7;
  const int s0  = (bid >> 3) * 128;

  const int e0 = sel[2 * b], e1 = sel[2 * b + 1];
  const float p0 = pscale[2 * b], p1 = pscale[2 * b + 1];

  const float* hbase = hidden + ((size_t)b * SS + s0) * HH;

  // ---- staging coords: thread loads 4 rows x 4 contiguous k (float4)
  const int srow = t >> 4;   // 0..31 (+32*p)
  const int skq  = t & 15;   // float4 index in 64-wide k slab

  float4 R[4];
  // GEMM1 per-lane w1 pointers (col = wc*64 + ct*16 + l15)
  const float* wp[4];
#pragma unroll
  for (int ct = 0; ct < 4; ++ct) {
    int cbase = wc * 64 + ct * 16;
    int ec = (cbase < 128) ? e0 : e1;
    int f  = (cbase & 127) + l15;
    wp[ct] = w1 + ((size_t)ec * FF + f) * HH + lk * 8;
  }

  f32x4 zero = {0.f, 0.f, 0.f, 0.f};
  f32x4 acc1[4][4];  // [rowtile][coltile]
#pragma unroll
  for (int i = 0; i < 4; ++i)
#pragma unroll
    for (int j = 0; j < 4; ++j) acc1[i][j] = zero;

  // prologue: stage k-slab 0
#pragma unroll
  for (int p = 0; p < 4; ++p)
    R[p] = *(const float4*)(hbase + (size_t)(srow + 32 * p) * HH + skq * 4);
#pragma unroll
  for (int p = 0; p < 4; ++p) {
    int row = srow + 32 * p;
    unsigned int lo = pk2(R[p].x, R[p].y), hi = pk2(R[p].z, R[p].w);
    int addr = row * 128 + ((skq * 8) ^ ((row & 7) << 4));
    *(uint2*)(&sA[0][addr]) = make_uint2(lo, hi);
  }
  __syncthreads();

  // ---- GEMM1 K loop: 32 iters x 64 k
  for (int it = 0; it < 32; ++it) {
    const int buf = it & 1;
    if (it < 31) {
      const int k0 = (it + 1) * 64;
#pragma unroll
      for (int p = 0; p < 4; ++p)
        R[p] = *(const float4*)(hbase + (size_t)(srow + 32 * p) * HH + k0 + skq * 4);
    }
#pragma unroll
    for (int kk = 0; kk < 2; ++kk) {
      const int kbyte = kk * 64 + lk * 16;
      bf16x8 a[4];
#pragma unroll
      for (int rt = 0; rt < 4; ++rt) {
        int row = wr * 64 + rt * 16 + l15;
        a[rt] = *(const bf16x8*)(&sA[buf][row * 128 + (kbyte ^ ((row & 7) << 4))]);
      }
#pragma unroll
      for (int ct = 0; ct < 4; ++ct) {
        const float* q = wp[ct] + it * 64 + kk * 32;
        float4 v0 = *(const float4*)q;
        float4 v1 = *(const float4*)(q + 4);
        bf16x8 bfr = pack8(v0, v1);
#pragma unroll
        for (int rt = 0; rt < 4; ++rt)
          acc1[rt][ct] = __builtin_amdgcn_mfma_f32_16x16x32_bf16(a[rt], bfr, acc1[rt][ct], 0, 0, 0);
      }
    }
    if (it < 31) {
#pragma unroll
      for (int p = 0; p < 4; ++p) {
        int row = srow + 32 * p;
        unsigned int lo = pk2(R[p].x, R[p].y), hi = pk2(R[p].z, R[p].w);
        int addr = row * 128 + ((skq * 8) ^ ((row & 7) << 4));
        *(uint2*)(&sA[buf ^ 1][addr]) = make_uint2(lo, hi);
      }
    }
    __syncthreads();
  }

  // ---- epilogue 1: bias + exact gelu + prob scale -> sG (bf16, swizzled)
#pragma unroll
  for (int ct = 0; ct < 4; ++ct) {
    int c = wc * 64 + ct * 16 + l15;
    int ec = (c < 128) ? e0 : e1;
    float pc = (c < 128) ? p0 : p1;
    float bias = b1[ec * FF + (c & 127)];
#pragma unroll
    for (int rt = 0; rt < 4; ++rt) {
#pragma unroll
      for (int r = 0; r < 4; ++r) {
        int row = wr * 64 + rt * 16 + lk * 4 + r;
        float x = acc1[rt][ct][r] + bias;
        float g = 0.5f * x * (1.0f + erff(x * 0.70710678118654752f));
        int addr = row * 512 + ((c * 2) ^ ((row & 7) << 4));
        *(u16*)(&sG[addr]) = f2bfu(pc * g);
      }
    }
  }
  __syncthreads();

  // ---- GEMM2: preload all A frags (4 rowtiles x 8 ksteps)
  bf16x8 pa[4][8];
#pragma unroll
  for (int rt = 0; rt < 4; ++rt) {
    int row = wr * 64 + rt * 16 + l15;
#pragma unroll
    for (int ks = 0; ks < 8; ++ks) {
      int cb = ks * 64 + lk * 16;
      pa[rt][ks] = *(const bf16x8*)(&sG[row * 512 + (cb ^ ((row & 7) << 4))]);
    }
  }

  float* obase = out + ((size_t)b * SS + s0) * HH;
  const size_t w2e0 = (size_t)e0 * HH * FF;
  const size_t w2e1 = (size_t)e1 * HH * FF;

  for (int ct = 0; ct < 32; ++ct) {
    const int h = wc * 512 + ct * 16 + l15;
    const float* q0 = w2 + w2e0 + (size_t)h * FF + lk * 8;
    const float* q1 = w2 + w2e1 + (size_t)h * FF + lk * 8;
    f32x4 acc[4];
#pragma unroll
    for (int rt = 0; rt < 4; ++rt) acc[rt] = zero;
#pragma unroll
    for (int ks = 0; ks < 8; ++ks) {
      const float* q = (ks < 4 ? q0 : q1) + (ks & 3) * 32;
      float4 v0 = *(const float4*)q;
      float4 v1 = *(const float4*)(q + 4);
      bf16x8 bfr = pack8(v0, v1);
#pragma unroll
      for (int rt = 0; rt < 4; ++rt)
        acc[rt] = __builtin_amdgcn_mfma_f32_16x16x32_bf16(pa[rt][ks], bfr, acc[rt], 0, 0, 0);
    }
    float bias = p0 * b2[(size_t)e0 * HH + h] + p1 * b2[(size_t)e1 * HH + h];
#pragma unroll
    for (int rt = 0; rt < 4; ++rt) {
#pragma unroll
      for (int r = 0; r < 4; ++r) {
        int row = wr * 64 + rt * 16 + lk * 4 + r;
        obase[(size_t)row * HH + h] = acc[rt][r] + bias;
      }
    }
  }
}

extern "C" void kernel_launch(void* const* d_in, const int* in_sizes, int n_in,
                              void* d_out, int out_size, void* d_ws, size_t ws_size,
                              hipStream_t stream) {
  const float* hidden   = (const float*)d_in[0];
  const float* router_w = (const float*)d_in[1];
  const float* router_b = (const float*)d_in[2];
  const float* w1       = (const float*)d_in[3];
  const float* b1       = (const float*)d_in[4];
  const float* w2       = (const float*)d_in[5];
  const float* b2       = (const float*)d_in[6];
  const float* counts   = (const float*)d_in[7];
  const float* drift    = (const float*)d_in[8];
  float* out            = (float*)d_out;

  float* logits = (float*)d_ws;          // 256 floats
  int*   sel    = (int*)(logits + 256);  // 16 ints
  float* pscale = logits + 272;          // 16 floats

  k_zero<<<1, 288, 0, stream>>>(logits);
  k_pool_logits<<<BB * 32, 256, 0, stream>>>(hidden, router_w, logits);
  k_topk<<<1, 256, 0, stream>>>(logits, router_b, counts, drift, sel, pscale, out);
  k_ffn<<<256, 512, 0, stream>>>(hidden, w1, b1, w2, b2, sel, pscale, out);
}

// Round 5
// 414.593 us; speedup vs baseline: 4.7199x; 1.3498x over previous
//
#include <hip/hip_runtime.h>
#include <hip/hip_bf16.h>

#define BB 8
#define SS 4096
#define HH 2048
#define EE 32
#define FF 128

constexpr size_t DELTA_N = (size_t)BB * SS * HH;  // 67108864
constexpr size_t WN = (size_t)EE * FF * HH;       // 8388608 elements per weight tensor

typedef short bf16x8 __attribute__((ext_vector_type(8)));
typedef float f32x4 __attribute__((ext_vector_type(4)));
typedef unsigned short u16;

__device__ __forceinline__ u16 f2bfu(float x) {
  unsigned int u = __float_as_uint(x);
  u = (u + 0x7FFFu + ((u >> 16) & 1u)) >> 16;  // RNE
  return (u16)u;
}

__device__ __forceinline__ unsigned int pk2(float a, float b) {
  union { __hip_bfloat162 h; unsigned int u; } c;
  c.h = __float22bfloat162_rn(make_float2(a, b));
  return c.u;  // low 16 = a, high 16 = b
}

__device__ __forceinline__ bf16x8 pack8(float4 a, float4 b) {
  union { bf16x8 v; unsigned int u[4]; } r;
  r.u[0] = pk2(a.x, a.y);
  r.u[1] = pk2(a.z, a.w);
  r.u[2] = pk2(b.x, b.y);
  r.u[3] = pk2(b.z, b.w);
  return r.v;
}

// ---------------- ws float layout ----------------
// [0..255] logits | [256..271] sel(int) | [272..287] pscale | byte 2048+: w1b, w2b (bf16)

__global__ void k_zero(float* __restrict__ ws) {
  if (threadIdx.x < 288) ws[threadIdx.x] = 0.0f;
}

// convert both weight tensors to bf16 (8 elems/thread, grid = 2*WN/8/256 blocks)
__global__ void k_cvt(const float* __restrict__ w1, const float* __restrict__ w2,
                      u16* __restrict__ w1b, u16* __restrict__ w2b) {
  size_t i = ((size_t)blockIdx.x * 256 + threadIdx.x) * 8;
  const float* src;
  u16* dst;
  if (i < WN) { src = w1 + i; dst = w1b + i; }
  else        { src = w2 + (i - WN); dst = w2b + (i - WN); }
  float4 a = *(const float4*)src;
  float4 b = *(const float4*)(src + 4);
  *(bf16x8*)dst = pack8(a, b);
}

// grid 512: b = bid>>6, hc = (bid>>3)&7, sq = bid&7. block 256.
__global__ void k_pool_logits(const float* __restrict__ hidden,
                              const float* __restrict__ rw,
                              float* __restrict__ logits) {
  const int b  = blockIdx.x >> 6;
  const int hc = (blockIdx.x >> 3) & 7;
  const int sq = blockIdx.x & 7;
  const int t  = threadIdx.x;
  const int tx = t & 63;   // float4 index over 256 h
  const int qq = t >> 6;   // s sub-chunk (128 rows each)
  const int h0 = hc * 256;

  const float* p = hidden + ((size_t)b * SS + sq * 512 + qq * 128) * HH + h0 + tx * 4;
  float4 s = make_float4(0.f, 0.f, 0.f, 0.f);
  for (int i = 0; i < 128; ++i) {
    float4 v = *(const float4*)(p + (size_t)i * HH);
    s.x += v.x; s.y += v.y; s.z += v.z; s.w += v.w;
  }
  __shared__ float ps[4][256];
  __shared__ float pl[256];
  *(float4*)&ps[qq][tx * 4] = s;
  __syncthreads();
  pl[t] = ps[0][t] + ps[1][t] + ps[2][t] + ps[3][t];
  __syncthreads();

  const int e = t >> 3, part = t & 7;
  const float* wrp = rw + (size_t)e * HH + h0 + part * 32;
  float v = 0.f;
#pragma unroll
  for (int m = 0; m < 32; ++m) v += pl[part * 32 + m] * wrp[m];
  v += __shfl_xor(v, 1, 8);
  v += __shfl_xor(v, 2, 8);
  v += __shfl_xor(v, 4, 8);
  if (part == 0) atomicAdd(&logits[b * EE + e], v * (1.0f / (float)SS));
}

__global__ void k_topk(const float* __restrict__ logits, const float* __restrict__ rb,
                       const float* __restrict__ counts, const float* __restrict__ drift,
                       int* __restrict__ sel, float* __restrict__ pscale,
                       float* __restrict__ out) {
  int t = threadIdx.x;
  int b = t >> 5, e = t & 31;
  float total = 0.0f, cmax = 0.0f, dmax = 0.0f;
  for (int i = 0; i < EE; ++i) {
    float c = counts[i]; total += c; cmax = fmaxf(cmax, c);
    float d = drift[i];  dmax = fmaxf(dmax, d);
  }
  float cnt = counts[e], dr = drift[e];
  float usage = cnt / fmaxf(total, 1e-8f);
  float bonus = (total > 0.0f) ? 0.1f * (1.0f - usage) : 0.0f;
  float un = cnt / fmaxf(cmax, 1e-8f);
  float dn = dr / fmaxf(dmax, 1e-8f);
  float l = logits[t] + rb[e] + bonus - 0.05f * (un + dn);

  float m = l;
  for (int w = 16; w; w >>= 1) m = fmaxf(m, __shfl_xor(m, w, 32));
  float p = expf(l - m);
  float ssum = p;
  for (int w = 16; w; w >>= 1) ssum += __shfl_xor(ssum, w, 32);
  float prob = p / ssum;
  out[DELTA_N + 32 + t] = prob;

  float v1 = prob; int i1 = e;
  for (int w = 16; w; w >>= 1) {
    float ov = __shfl_xor(v1, w, 32); int oi = __shfl_xor(i1, w, 32);
    if (ov > v1 || (ov == v1 && oi < i1)) { v1 = ov; i1 = oi; }
  }
  float v2 = (e == i1) ? -1.0f : prob; int i2 = e;
  for (int w = 16; w; w >>= 1) {
    float ov = __shfl_xor(v2, w, 32); int oi = __shfl_xor(i2, w, 32);
    if (ov > v2 || (ov == v2 && oi < i2)) { v2 = ov; i2 = oi; }
  }
  if (e == 0) {
    float denom = fmaxf(v1 + v2, 1e-8f);
    float tp0 = v1 / denom, tp1 = v2 / denom;
    sel[b * 2 + 0] = i1;
    sel[b * 2 + 1] = i2;
    pscale[b * 2 + 0] = tp0;
    pscale[b * 2 + 1] = tp1;
    out[DELTA_N + 0 + b * 2 + 0] = (float)i1;
    out[DELTA_N + 0 + b * 2 + 1] = (float)i2;
    out[DELTA_N + 16 + b * 2 + 0] = tp0;
    out[DELTA_N + 16 + b * 2 + 1] = tp1;
  }
}

// ---------------- MFMA fused expert FFN ----------------
// grid 512: b = bid&7 (XCD affinity), s0 = (bid>>3)*64. 512 threads = 8 waves (2x4).
// GEMM1: M=64, N=256, K=2048. GEMM2: M=64, N=2048, K=256.
template <bool W16>
__global__ __launch_bounds__(512, 2) void k_ffn(
    const float* __restrict__ hidden, const float* __restrict__ w1,
    const float* __restrict__ b1, const float* __restrict__ w2,
    const float* __restrict__ b2, const u16* __restrict__ w1b,
    const u16* __restrict__ w2b, const int* __restrict__ sel,
    const float* __restrict__ pscale, float* __restrict__ out) {
  __shared__ unsigned char sA[2][64 * 128];  // [buf][row*128B + (kbyte ^ ((row&7)<<4))]
  __shared__ unsigned char sG[64 * 512];     // row*512B + (cbyte ^ ((row&7)<<4))

  const int t    = threadIdx.x;
  const int lane = t & 63;
  const int wv   = t >> 6;
  const int wr   = wv >> 2;   // 0..1
  const int wc   = wv & 3;    // 0..3
  const int l15  = lane & 15;
  const int lk   = lane >> 4; // 0..3

  const int bid = blockIdx.x;
  const int b   = bid & 7;
  const int s0  = (bid >> 3) * 64;

  const int e0 = sel[2 * b], e1 = sel[2 * b + 1];
  const float p0 = pscale[2 * b], p1 = pscale[2 * b + 1];

  const float* hbase = hidden + ((size_t)b * SS + s0) * HH;

  const int srow = t >> 4;  // 0..31 (+32)
  const int skq  = t & 15;

  float4 R[2];

  const float* wp[4];
  const u16*   wpb[4];
#pragma unroll
  for (int ct = 0; ct < 4; ++ct) {
    int cbase = wc * 64 + ct * 16;
    int ec = (cbase < 128) ? e0 : e1;
    int f  = (cbase & 127) + l15;
    if (W16) wpb[ct] = w1b + ((size_t)ec * FF + f) * HH + lk * 8;
    else     wp[ct]  = w1  + ((size_t)ec * FF + f) * HH + lk * 8;
  }

  f32x4 zero = {0.f, 0.f, 0.f, 0.f};
  f32x4 acc1[2][4];
#pragma unroll
  for (int i = 0; i < 2; ++i)
#pragma unroll
    for (int j = 0; j < 4; ++j) acc1[i][j] = zero;

  // prologue: stage k-slab 0
#pragma unroll
  for (int p = 0; p < 2; ++p)
    R[p] = *(const float4*)(hbase + (size_t)(srow + 32 * p) * HH + skq * 4);
#pragma unroll
  for (int p = 0; p < 2; ++p) {
    int row = srow + 32 * p;
    int addr = row * 128 + ((skq * 8) ^ ((row & 7) << 4));
    *(uint2*)(&sA[0][addr]) = make_uint2(pk2(R[p].x, R[p].y), pk2(R[p].z, R[p].w));
  }
  __syncthreads();

  // ---- GEMM1 K loop: 32 iters x 64 k
  for (int it = 0; it < 32; ++it) {
    const int buf = it & 1;
    if (it < 31) {
      const int k0 = (it + 1) * 64;
#pragma unroll
      for (int p = 0; p < 2; ++p)
        R[p] = *(const float4*)(hbase + (size_t)(srow + 32 * p) * HH + k0 + skq * 4);
    }
#pragma unroll
    for (int kk = 0; kk < 2; ++kk) {
      bf16x8 a[2];
#pragma unroll
      for (int rt = 0; rt < 2; ++rt) {
        int row = wr * 32 + rt * 16 + l15;
        a[rt] = *(const bf16x8*)(&sA[buf][row * 128 + ((kk * 64 + lk * 16) ^ ((row & 7) << 4))]);
      }
#pragma unroll
      for (int ct = 0; ct < 4; ++ct) {
        bf16x8 bfr;
        if (W16) {
          bfr = *(const bf16x8*)(wpb[ct] + it * 64 + kk * 32);
        } else {
          const float* q = wp[ct] + it * 64 + kk * 32;
          bfr = pack8(*(const float4*)q, *(const float4*)(q + 4));
        }
#pragma unroll
        for (int rt = 0; rt < 2; ++rt)
          acc1[rt][ct] = __builtin_amdgcn_mfma_f32_16x16x32_bf16(a[rt], bfr, acc1[rt][ct], 0, 0, 0);
      }
    }
    if (it < 31) {
#pragma unroll
      for (int p = 0; p < 2; ++p) {
        int row = srow + 32 * p;
        int addr = row * 128 + ((skq * 8) ^ ((row & 7) << 4));
        *(uint2*)(&sA[buf ^ 1][addr]) = make_uint2(pk2(R[p].x, R[p].y), pk2(R[p].z, R[p].w));
      }
    }
    __syncthreads();
  }

  // ---- epilogue 1: bias + exact gelu + prob scale -> sG (bf16, swizzled)
#pragma unroll
  for (int ct = 0; ct < 4; ++ct) {
    int c = wc * 64 + ct * 16 + l15;
    int ec = (c < 128) ? e0 : e1;
    float pc = (c < 128) ? p0 : p1;
    float bias = b1[ec * FF + (c & 127)];
#pragma unroll
    for (int rt = 0; rt < 2; ++rt) {
#pragma unroll
      for (int r = 0; r < 4; ++r) {
        int row = wr * 32 + rt * 16 + lk * 4 + r;
        float x = acc1[rt][ct][r] + bias;
        float g = 0.5f * x * (1.0f + erff(x * 0.70710678118654752f));
        int addr = row * 512 + ((c * 2) ^ ((row & 7) << 4));
        *(u16*)(&sG[addr]) = f2bfu(pc * g);
      }
    }
  }
  __syncthreads();

  // ---- GEMM2: preload all A frags (2 rowtiles x 8 ksteps = 64 VGPR)
  bf16x8 pa[2][8];
#pragma unroll
  for (int rt = 0; rt < 2; ++rt) {
    int row = wr * 32 + rt * 16 + l15;
#pragma unroll
    for (int ks = 0; ks < 8; ++ks)
      pa[rt][ks] = *(const bf16x8*)(&sG[row * 512 + ((ks * 64 + lk * 16) ^ ((row & 7) << 4))]);
  }

  float* obase = out + ((size_t)b * SS + s0) * HH;

  for (int ct = 0; ct < 32; ++ct) {
    const int h = wc * 512 + ct * 16 + l15;
    f32x4 acc[2];
    acc[0] = zero; acc[1] = zero;
    if (W16) {
      const u16* qb0 = w2b + ((size_t)e0 * HH + h) * FF + lk * 8;
      const u16* qb1 = w2b + ((size_t)e1 * HH + h) * FF + lk * 8;
#pragma unroll
      for (int ks = 0; ks < 8; ++ks) {
        bf16x8 bfr = *(const bf16x8*)((ks < 4 ? qb0 : qb1) + (ks & 3) * 32);
#pragma unroll
        for (int rt = 0; rt < 2; ++rt)
          acc[rt] = __builtin_amdgcn_mfma_f32_16x16x32_bf16(pa[rt][ks], bfr, acc[rt], 0, 0, 0);
      }
    } else {
      const float* q0 = w2 + ((size_t)e0 * HH + h) * FF + lk * 8;
      const float* q1 = w2 + ((size_t)e1 * HH + h) * FF + lk * 8;
#pragma unroll
      for (int ks = 0; ks < 8; ++ks) {
        const float* q = (ks < 4 ? q0 : q1) + (ks & 3) * 32;
        bf16x8 bfr = pack8(*(const float4*)q, *(const float4*)(q + 4));
#pragma unroll
        for (int rt = 0; rt < 2; ++rt)
          acc[rt] = __builtin_amdgcn_mfma_f32_16x16x32_bf16(pa[rt][ks], bfr, acc[rt], 0, 0, 0);
      }
    }
    float bias = p0 * b2[(size_t)e0 * HH + h] + p1 * b2[(size_t)e1 * HH + h];
#pragma unroll
    for (int rt = 0; rt < 2; ++rt) {
#pragma unroll
      for (int r = 0; r < 4; ++r) {
        int row = wr * 32 + rt * 16 + lk * 4 + r;
        obase[(size_t)row * HH + h] = acc[rt][r] + bias;
      }
    }
  }
}

extern "C" void kernel_launch(void* const* d_in, const int* in_sizes, int n_in,
                              void* d_out, int out_size, void* d_ws, size_t ws_size,
                              hipStream_t stream) {
  const float* hidden   = (const float*)d_in[0];
  const float* router_w = (const float*)d_in[1];
  const float* router_b = (const float*)d_in[2];
  const float* w1       = (const float*)d_in[3];
  const float* b1       = (const float*)d_in[4];
  const float* w2       = (const float*)d_in[5];
  const float* b2       = (const float*)d_in[6];
  const float* counts   = (const float*)d_in[7];
  const float* drift    = (const float*)d_in[8];
  float* out            = (float*)d_out;

  float* logits = (float*)d_ws;
  int*   sel    = (int*)(logits + 256);
  float* pscale = logits + 272;
  u16*   w1b    = (u16*)((char*)d_ws + 2048);
  u16*   w2b    = w1b + WN;

  const size_t need = 2048 + 2 * WN * sizeof(u16) + 64;
  const bool useW16 = ws_size >= need;

  k_zero<<<1, 288, 0, stream>>>(logits);
  if (useW16) k_cvt<<<(int)(2 * WN / 8 / 256), 256, 0, stream>>>(w1, w2, w1b, w2b);
  k_pool_logits<<<512, 256, 0, stream>>>(hidden, router_w, logits);
  k_topk<<<1, 256, 0, stream>>>(logits, router_b, counts, drift, sel, pscale, out);
  if (useW16)
    k_ffn<true><<<512, 512, 0, stream>>>(hidden, w1, b1, w2, b2, w1b, w2b, sel, pscale, out);
  else
    k_ffn<false><<<512, 512, 0, stream>>>(hidden, w1, b1, w2, b2, w1b, w2b, sel, pscale, out);
}

// Round 6
// 271.865 us; speedup vs baseline: 7.1979x; 1.5250x over previous
//
#include <hip/hip_runtime.h>
#include <hip/hip_bf16.h>

#define BB 8
#define SS 4096
#define HH 2048
#define EE 32
#define FF 128

constexpr size_t DELTA_N = (size_t)BB * SS * HH;  // 67108864
constexpr size_t WELEM = (size_t)EE * FF * HH;    // 8388608 elems per weight tensor
constexpr size_t WBYTES = WELEM * 2;              // 16 MB packed bf16

typedef short bf16x8 __attribute__((ext_vector_type(8)));
typedef float f32x4 __attribute__((ext_vector_type(4)));
typedef unsigned short u16;
typedef __attribute__((address_space(3))) unsigned char as3u8;
typedef __attribute__((address_space(1))) const unsigned char as1u8;

__device__ __forceinline__ u16 f2bfu(float x) {
  unsigned int u = __float_as_uint(x);
  u = (u + 0x7FFFu + ((u >> 16) & 1u)) >> 16;  // RNE
  return (u16)u;
}

__device__ __forceinline__ unsigned int pk2(float a, float b) {
  union { __hip_bfloat162 h; unsigned int u; } c;
  c.h = __float22bfloat162_rn(make_float2(a, b));
  return c.u;  // low 16 = a, high 16 = b
}

__device__ __forceinline__ bf16x8 pack8(float4 a, float4 b) {
  union { bf16x8 v; unsigned int u[4]; } r;
  r.u[0] = pk2(a.x, a.y);
  r.u[1] = pk2(a.z, a.w);
  r.u[2] = pk2(b.x, b.y);
  r.u[3] = pk2(b.z, b.w);
  return r.v;
}

__device__ __forceinline__ uint4 cvt4(float4 a, float4 b) {
  return make_uint4(pk2(a.x, a.y), pk2(a.z, a.w), pk2(b.x, b.y), pk2(b.z, b.w));
}

__device__ __forceinline__ void glds16(const void* g, void* l) {
  __builtin_amdgcn_global_load_lds((as1u8*)g, (as3u8*)l, 16, 0, 0);
}

// ---------------- router (unchanged, proven) ----------------
__global__ void k_zero(float* __restrict__ ws) {
  if (threadIdx.x < 288) ws[threadIdx.x] = 0.0f;
}

__global__ void k_pool_logits(const float* __restrict__ hidden,
                              const float* __restrict__ rw,
                              float* __restrict__ logits) {
  const int b  = blockIdx.x >> 6;
  const int hc = (blockIdx.x >> 3) & 7;
  const int sq = blockIdx.x & 7;
  const int t  = threadIdx.x;
  const int tx = t & 63;
  const int qq = t >> 6;
  const int h0 = hc * 256;

  const float* p = hidden + ((size_t)b * SS + sq * 512 + qq * 128) * HH + h0 + tx * 4;
  float4 s = make_float4(0.f, 0.f, 0.f, 0.f);
  for (int i = 0; i < 128; ++i) {
    float4 v = *(const float4*)(p + (size_t)i * HH);
    s.x += v.x; s.y += v.y; s.z += v.z; s.w += v.w;
  }
  __shared__ float ps[4][256];
  __shared__ float pl[256];
  *(float4*)&ps[qq][tx * 4] = s;
  __syncthreads();
  pl[t] = ps[0][t] + ps[1][t] + ps[2][t] + ps[3][t];
  __syncthreads();

  const int e = t >> 3, part = t & 7;
  const float* wrp = rw + (size_t)e * HH + h0 + part * 32;
  float v = 0.f;
#pragma unroll
  for (int m = 0; m < 32; ++m) v += pl[part * 32 + m] * wrp[m];
  v += __shfl_xor(v, 1, 8);
  v += __shfl_xor(v, 2, 8);
  v += __shfl_xor(v, 4, 8);
  if (part == 0) atomicAdd(&logits[b * EE + e], v * (1.0f / (float)SS));
}

__global__ void k_topk(const float* __restrict__ logits, const float* __restrict__ rb,
                       const float* __restrict__ counts, const float* __restrict__ drift,
                       int* __restrict__ sel, float* __restrict__ pscale,
                       float* __restrict__ out) {
  int t = threadIdx.x;
  int b = t >> 5, e = t & 31;
  float total = 0.0f, cmax = 0.0f, dmax = 0.0f;
  for (int i = 0; i < EE; ++i) {
    float c = counts[i]; total += c; cmax = fmaxf(cmax, c);
    float d = drift[i];  dmax = fmaxf(dmax, d);
  }
  float cnt = counts[e], dr = drift[e];
  float usage = cnt / fmaxf(total, 1e-8f);
  float bonus = (total > 0.0f) ? 0.1f * (1.0f - usage) : 0.0f;
  float un = cnt / fmaxf(cmax, 1e-8f);
  float dn = dr / fmaxf(dmax, 1e-8f);
  float l = logits[t] + rb[e] + bonus - 0.05f * (un + dn);

  float m = l;
  for (int w = 16; w; w >>= 1) m = fmaxf(m, __shfl_xor(m, w, 32));
  float p = expf(l - m);
  float ssum = p;
  for (int w = 16; w; w >>= 1) ssum += __shfl_xor(ssum, w, 32);
  float prob = p / ssum;
  out[DELTA_N + 32 + t] = prob;

  float v1 = prob; int i1 = e;
  for (int w = 16; w; w >>= 1) {
    float ov = __shfl_xor(v1, w, 32); int oi = __shfl_xor(i1, w, 32);
    if (ov > v1 || (ov == v1 && oi < i1)) { v1 = ov; i1 = oi; }
  }
  float v2 = (e == i1) ? -1.0f : prob; int i2 = e;
  for (int w = 16; w; w >>= 1) {
    float ov = __shfl_xor(v2, w, 32); int oi = __shfl_xor(i2, w, 32);
    if (ov > v2 || (ov == v2 && oi < i2)) { v2 = ov; i2 = oi; }
  }
  if (e == 0) {
    float denom = fmaxf(v1 + v2, 1e-8f);
    float tp0 = v1 / denom, tp1 = v2 / denom;
    sel[b * 2 + 0] = i1;
    sel[b * 2 + 1] = i2;
    pscale[b * 2 + 0] = tp0;
    pscale[b * 2 + 1] = tp1;
    out[DELTA_N + 0 + b * 2 + 0] = (float)i1;
    out[DELTA_N + 0 + b * 2 + 1] = (float)i2;
    out[DELTA_N + 16 + b * 2 + 0] = tp0;
    out[DELTA_N + 16 + b * 2 + 1] = tp1;
  }
}

// ---------------- k_pack: weights -> bf16 LDS-image order ----------------
// w1p per expert: 32 K-slab images of 16KB; image byte = col*128 + (kbyte ^ ((col&7)<<4)),
//   content = bf16(w1[e][col][it*64 + kbyte/2]).
// w2p per expert: 2048 rows of 256B; row byte = (f*2) ^ ((h&7)<<4).
__global__ void k_pack(const float* __restrict__ w1, const float* __restrict__ w2,
                       u16* __restrict__ w1p, u16* __restrict__ w2p) {
  unsigned c = blockIdx.x * 256 + threadIdx.x;  // 16B chunk id, 2M total
  const float* src;
  u16* dst;
  if (c < 1048576u) {
    unsigned e = c >> 15, ci = c & 32767u;
    unsigned it = ci >> 10;
    unsigned cb = (ci & 1023u) * 16u;
    unsigned col = cb >> 7;
    unsigned kb = (cb & 127u) ^ ((col & 7u) << 4);
    unsigned k = it * 64u + (kb >> 1);
    src = w1 + ((size_t)(e * 128u + col) * HH + k);
    dst = w1p + (size_t)c * 8;
  } else {
    unsigned c2 = c - 1048576u;
    unsigned e = c2 >> 15, ci = c2 & 32767u;
    unsigned h = ci >> 4;
    unsigned cb = (ci & 15u) * 16u;
    unsigned kb = cb ^ ((h & 7u) << 4);
    unsigned f = kb >> 1;
    src = w2 + ((size_t)(e * 2048u + h) * FF + f);
    dst = w2p + (size_t)c2 * 8;
  }
  float4 a = *(const float4*)src;
  float4 b = *(const float4*)(src + 4);
  *(bf16x8*)dst = pack8(a, b);
}

// ---------------- k_ffn2: canonical LDS-staged MFMA FFN ----------------
// grid 256 (= 1/CU): b = bid&7, s0 = (bid>>3)*128. 512 thr = 8 waves (2 wr x 4 wc),
// per-wave 64x64 output tile. GEMM1 M=128 N=256 K=2048; GEMM2 M=128 N=2048 K=256.
// LDS (128KB): sA dbuf [0,32K), sB dbuf [32K,96K); then sG [0,64K), w2 tiles [64K,128K).
#define SB_OFF 32768
#define T_OFF 65536

__global__ __launch_bounds__(512, 2) void k_ffn2(
    const float* __restrict__ hidden, const float* __restrict__ bs1,
    const float* __restrict__ bs2, const u16* __restrict__ w1p,
    const u16* __restrict__ w2p, const int* __restrict__ sel,
    const float* __restrict__ pscale, float* __restrict__ out) {
  __shared__ __align__(16) char smem[131072];

  const int t    = threadIdx.x;
  const int lane = t & 63;
  const int wv   = t >> 6;     // 0..7
  const int wr   = wv >> 2;    // 0..1
  const int wc   = wv & 3;     // 0..3
  const int l15  = lane & 15;
  const int lk   = lane >> 4;  // 0..3

  const int bid = blockIdx.x;
  const int b   = bid & 7;
  const int s0  = (bid >> 3) * 128;

  const int e0 = sel[2 * b], e1 = sel[2 * b + 1];
  const float p0 = pscale[2 * b], p1 = pscale[2 * b + 1];

  const int RB  = wr * 64;   // wave row base
  const int CBc = wc * 64;   // GEMM1 wave col base
  const int CB2 = wc * 32;   // GEMM2 wave col base (within 128-col tile)

  const char* w1pb = (const char*)w1p;
  const char* w2pb = (const char*)w2p;

  // A staging coords: 128 rows x 64 k f32 per iter / 512 thr = 16 floats each
  const int arow = t >> 2;
  const int akq2 = (t & 3) * 32;  // bf16 byte offset of this thread's 16-elem run
  const float* hA = hidden + ((size_t)b * SS + s0 + arow) * HH + (t & 3) * 16;
  const unsigned swA = (arow & 7) << 4;

  // GEMM1 B staging source (per wave 4KB chunk of the 32KB tile)
  const size_t esel = (size_t)(wv < 4 ? e0 : e1);
  const char* w1src = w1pb + esel * 524288 + (size_t)(wv & 3) * 4096 + (size_t)lane * 16;
  char* sbW = &smem[SB_OFF + wv * 4096];

  f32x4 zero = {0.f, 0.f, 0.f, 0.f};
  f32x4 acc1[4][4];
#pragma unroll
  for (int i = 0; i < 4; ++i)
#pragma unroll
    for (int j = 0; j < 4; ++j) acc1[i][j] = zero;

  // ---- prologue: stage A(0), B(0)
  {
    float4 P[4];
#pragma unroll
    for (int q = 0; q < 4; ++q) P[q] = *(const float4*)(hA + q * 4);
#pragma unroll
    for (int r = 0; r < 4; ++r) glds16(w1src + r * 1024, sbW + r * 1024);
    char* da = &smem[arow * 128];
    *(uint4*)(da + (akq2 ^ swA)) = cvt4(P[0], P[1]);
    *(uint4*)(da + ((akq2 + 16) ^ swA)) = cvt4(P[2], P[3]);
  }
  __syncthreads();

  // ---- GEMM1 main loop: 32 iters x K=64
  for (int j = 0; j < 32; ++j) {
    const int cb = j & 1, nb = cb ^ 1;
    float4 P[4];
    if (j < 31) {
      const float* hp = hA + (j + 1) * 64;
#pragma unroll
      for (int q = 0; q < 4; ++q) P[q] = *(const float4*)(hp + q * 4);
      const char* s = w1src + (size_t)(j + 1) * 16384;
      char* d = sbW + nb * 32768;
#pragma unroll
      for (int r = 0; r < 4; ++r) glds16(s + r * 1024, d + r * 1024);
    }
    const char* sa = &smem[cb * 16384];
    const char* sb = &smem[SB_OFF + cb * 32768];
#pragma unroll
    for (int kk = 0; kk < 2; ++kk) {
      bf16x8 af[4], bfv[4];
#pragma unroll
      for (int rt = 0; rt < 4; ++rt) {
        int row = RB + rt * 16 + l15;
        af[rt] = *(const bf16x8*)(sa + row * 128 + ((kk * 64 + lk * 16) ^ ((row & 7) << 4)));
      }
#pragma unroll
      for (int ct = 0; ct < 4; ++ct) {
        int col = CBc + ct * 16 + l15;
        bfv[ct] = *(const bf16x8*)(sb + col * 128 + ((kk * 64 + lk * 16) ^ ((col & 7) << 4)));
      }
#pragma unroll
      for (int rt = 0; rt < 4; ++rt)
#pragma unroll
        for (int ct = 0; ct < 4; ++ct)
          acc1[rt][ct] = __builtin_amdgcn_mfma_f32_16x16x32_bf16(af[rt], bfv[ct], acc1[rt][ct], 0, 0, 0);
    }
    if (j < 31) {
      char* da = &smem[nb * 16384 + arow * 128];
      *(uint4*)(da + (akq2 ^ swA)) = cvt4(P[0], P[1]);
      *(uint4*)(da + ((akq2 + 16) ^ swA)) = cvt4(P[2], P[3]);
    }
    __syncthreads();
  }

  // ---- epilogue 1: bias + exact gelu + prob scale -> sG [0,64K)
#pragma unroll
  for (int ct = 0; ct < 4; ++ct) {
    int c = CBc + ct * 16 + l15;
    int ec = (c < 128) ? e0 : e1;
    float pc = (c < 128) ? p0 : p1;
    float bias = bs1[ec * FF + (c & 127)];
#pragma unroll
    for (int rt = 0; rt < 4; ++rt)
#pragma unroll
      for (int r = 0; r < 4; ++r) {
        int row = RB + rt * 16 + lk * 4 + r;
        float x = acc1[rt][ct][r] + bias;
        float g = 0.5f * x * (1.0f + erff(x * 0.70710678118654752f));
        *(u16*)&smem[row * 512 + ((c * 2) ^ ((row & 7) << 4))] = f2bfu(pc * g);
      }
  }
  // stage w2 tile (n0=0, e0 half) while sG settles
  {
    const char* s = w2pb + (size_t)e0 * 524288 + (size_t)wv * 4096 + (size_t)lane * 16;
    char* d = &smem[T_OFF + wv * 4096];
#pragma unroll
    for (int r = 0; r < 4; ++r) glds16(s + r * 1024, d + r * 1024);
  }
  __syncthreads();

  // ---- GEMM2: preload all g1 A-frags (4 rt x 8 ks = 128 VGPR)
  bf16x8 pa[4][8];
#pragma unroll
  for (int rt = 0; rt < 4; ++rt) {
    int row = RB + rt * 16 + l15;
    unsigned sw = (row & 7) << 4;
#pragma unroll
    for (int ks = 0; ks < 8; ++ks)
      pa[rt][ks] = *(const bf16x8*)&smem[row * 512 + ((ks * 64 + lk * 16) ^ sw)];
  }

  float* obase = out + ((size_t)b * SS + s0) * HH;
  const char* gsrc_w = w2pb + (size_t)wv * 4096 + (size_t)lane * 16;

#pragma unroll 1
  for (int n0 = 0; n0 < 16; ++n0) {
    f32x4 acc2[4][2];
#pragma unroll
    for (int i = 0; i < 4; ++i) { acc2[i][0] = zero; acc2[i][1] = zero; }

    // ---- half 0: compute T0 (e0, f 0-127); stage T1 (e1, same n0)
    {
      const char* s = gsrc_w + (size_t)e1 * 524288 + (size_t)n0 * 32768;
      char* d = &smem[T_OFF + 32768 + wv * 4096];
#pragma unroll
      for (int r = 0; r < 4; ++r) glds16(s + r * 1024, d + r * 1024);
    }
    {
      const char* tb = &smem[T_OFF];
#pragma unroll
      for (int ks = 0; ks < 4; ++ks) {
        bf16x8 bfv[2];
#pragma unroll
        for (int ct = 0; ct < 2; ++ct) {
          int col = CB2 + ct * 16 + l15;
          bfv[ct] = *(const bf16x8*)(tb + col * 256 + ((ks * 64 + lk * 16) ^ ((col & 7) << 4)));
        }
#pragma unroll
        for (int rt = 0; rt < 4; ++rt)
#pragma unroll
          for (int ct = 0; ct < 2; ++ct)
            acc2[rt][ct] = __builtin_amdgcn_mfma_f32_16x16x32_bf16(pa[rt][ks], bfv[ct], acc2[rt][ct], 0, 0, 0);
      }
    }
    __syncthreads();

    // ---- half 1: compute T1 (e1, f 0-127); stage T0 for n0+1 (e0)
    if (n0 < 15) {
      const char* s = gsrc_w + (size_t)e0 * 524288 + (size_t)(n0 + 1) * 32768;
      char* d = &smem[T_OFF + wv * 4096];
#pragma unroll
      for (int r = 0; r < 4; ++r) glds16(s + r * 1024, d + r * 1024);
    }
    {
      const char* tb = &smem[T_OFF + 32768];
#pragma unroll
      for (int ks = 0; ks < 4; ++ks) {
        bf16x8 bfv[2];
#pragma unroll
        for (int ct = 0; ct < 2; ++ct) {
          int col = CB2 + ct * 16 + l15;
          bfv[ct] = *(const bf16x8*)(tb + col * 256 + ((ks * 64 + lk * 16) ^ ((col & 7) << 4)));
        }
#pragma unroll
        for (int rt = 0; rt < 4; ++rt)
#pragma unroll
          for (int ct = 0; ct < 2; ++ct)
            acc2[rt][ct] = __builtin_amdgcn_mfma_f32_16x16x32_bf16(pa[rt][4 + ks], bfv[ct], acc2[rt][ct], 0, 0, 0);
      }
    }
    // ---- bias + store 128 cols
#pragma unroll
    for (int ct = 0; ct < 2; ++ct) {
      int h = n0 * 128 + CB2 + ct * 16 + l15;
      float bias = p0 * bs2[(size_t)e0 * HH + h] + p1 * bs2[(size_t)e1 * HH + h];
#pragma unroll
      for (int rt = 0; rt < 4; ++rt)
#pragma unroll
        for (int r = 0; r < 4; ++r) {
          int row = RB + rt * 16 + lk * 4 + r;
          obase[(size_t)row * HH + h] = acc2[rt][ct][r] + bias;
        }
    }
    __syncthreads();
  }
}

// ---------------- fallback (round-5 f32 path, proven) ----------------
__global__ __launch_bounds__(512, 2) void k_ffn_fb(
    const float* __restrict__ hidden, const float* __restrict__ w1,
    const float* __restrict__ b1, const float* __restrict__ w2,
    const float* __restrict__ b2, const int* __restrict__ sel,
    const float* __restrict__ pscale, float* __restrict__ out) {
  __shared__ unsigned char sA[2][64 * 128];
  __shared__ unsigned char sG[64 * 512];

  const int t    = threadIdx.x;
  const int lane = t & 63;
  const int wv   = t >> 6;
  const int wr   = wv >> 2;
  const int wc   = wv & 3;
  const int l15  = lane & 15;
  const int lk   = lane >> 4;

  const int bid = blockIdx.x;
  const int b   = bid & 7;
  const int s0  = (bid >> 3) * 64;

  const int e0 = sel[2 * b], e1 = sel[2 * b + 1];
  const float p0 = pscale[2 * b], p1 = pscale[2 * b + 1];

  const float* hbase = hidden + ((size_t)b * SS + s0) * HH;
  const int srow = t >> 4;
  const int skq  = t & 15;

  float4 R[2];
  const float* wp[4];
#pragma unroll
  for (int ct = 0; ct < 4; ++ct) {
    int cbase = wc * 64 + ct * 16;
    int ec = (cbase < 128) ? e0 : e1;
    int f  = (cbase & 127) + l15;
    wp[ct] = w1 + ((size_t)ec * FF + f) * HH + lk * 8;
  }

  f32x4 zero = {0.f, 0.f, 0.f, 0.f};
  f32x4 acc1[2][4];
#pragma unroll
  for (int i = 0; i < 2; ++i)
#pragma unroll
    for (int j = 0; j < 4; ++j) acc1[i][j] = zero;

#pragma unroll
  for (int p = 0; p < 2; ++p)
    R[p] = *(const float4*)(hbase + (size_t)(srow + 32 * p) * HH + skq * 4);
#pragma unroll
  for (int p = 0; p < 2; ++p) {
    int row = srow + 32 * p;
    int addr = row * 128 + ((skq * 8) ^ ((row & 7) << 4));
    *(uint2*)(&sA[0][addr]) = make_uint2(pk2(R[p].x, R[p].y), pk2(R[p].z, R[p].w));
  }
  __syncthreads();

  for (int it = 0; it < 32; ++it) {
    const int buf = it & 1;
    if (it < 31) {
      const int k0 = (it + 1) * 64;
#pragma unroll
      for (int p = 0; p < 2; ++p)
        R[p] = *(const float4*)(hbase + (size_t)(srow + 32 * p) * HH + k0 + skq * 4);
    }
#pragma unroll
    for (int kk = 0; kk < 2; ++kk) {
      bf16x8 a[2];
#pragma unroll
      for (int rt = 0; rt < 2; ++rt) {
        int row = wr * 32 + rt * 16 + l15;
        a[rt] = *(const bf16x8*)(&sA[buf][row * 128 + ((kk * 64 + lk * 16) ^ ((row & 7) << 4))]);
      }
#pragma unroll
      for (int ct = 0; ct < 4; ++ct) {
        const float* q = wp[ct] + it * 64 + kk * 32;
        bf16x8 bfr = pack8(*(const float4*)q, *(const float4*)(q + 4));
#pragma unroll
        for (int rt = 0; rt < 2; ++rt)
          acc1[rt][ct] = __builtin_amdgcn_mfma_f32_16x16x32_bf16(a[rt], bfr, acc1[rt][ct], 0, 0, 0);
      }
    }
    if (it < 31) {
#pragma unroll
      for (int p = 0; p < 2; ++p) {
        int row = srow + 32 * p;
        int addr = row * 128 + ((skq * 8) ^ ((row & 7) << 4));
        *(uint2*)(&sA[buf ^ 1][addr]) = make_uint2(pk2(R[p].x, R[p].y), pk2(R[p].z, R[p].w));
      }
    }
    __syncthreads();
  }

#pragma unroll
  for (int ct = 0; ct < 4; ++ct) {
    int c = wc * 64 + ct * 16 + l15;
    int ec = (c < 128) ? e0 : e1;
    float pc = (c < 128) ? p0 : p1;
    float bias = b1[ec * FF + (c & 127)];
#pragma unroll
    for (int rt = 0; rt < 2; ++rt)
#pragma unroll
      for (int r = 0; r < 4; ++r) {
        int row = wr * 32 + rt * 16 + lk * 4 + r;
        float x = acc1[rt][ct][r] + bias;
        float g = 0.5f * x * (1.0f + erff(x * 0.70710678118654752f));
        int addr = row * 512 + ((c * 2) ^ ((row & 7) << 4));
        *(u16*)(&sG[addr]) = f2bfu(pc * g);
      }
  }
  __syncthreads();

  bf16x8 pa[2][8];
#pragma unroll
  for (int rt = 0; rt < 2; ++rt) {
    int row = wr * 32 + rt * 16 + l15;
#pragma unroll
    for (int ks = 0; ks < 8; ++ks)
      pa[rt][ks] = *(const bf16x8*)(&sG[row * 512 + ((ks * 64 + lk * 16) ^ ((row & 7) << 4))]);
  }

  float* obase = out + ((size_t)b * SS + s0) * HH;
  for (int ct = 0; ct < 32; ++ct) {
    const int h = wc * 512 + ct * 16 + l15;
    f32x4 acc[2];
    acc[0] = zero; acc[1] = zero;
    const float* q0 = w2 + ((size_t)e0 * HH + h) * FF + lk * 8;
    const float* q1 = w2 + ((size_t)e1 * HH + h) * FF + lk * 8;
#pragma unroll
    for (int ks = 0; ks < 8; ++ks) {
      const float* q = (ks < 4 ? q0 : q1) + (ks & 3) * 32;
      bf16x8 bfr = pack8(*(const float4*)q, *(const float4*)(q + 4));
#pragma unroll
      for (int rt = 0; rt < 2; ++rt)
        acc[rt] = __builtin_amdgcn_mfma_f32_16x16x32_bf16(pa[rt][ks], bfr, acc[rt], 0, 0, 0);
    }
    float bias = p0 * b2[(size_t)e0 * HH + h] + p1 * b2[(size_t)e1 * HH + h];
#pragma unroll
    for (int rt = 0; rt < 2; ++rt)
#pragma unroll
      for (int r = 0; r < 4; ++r) {
        int row = wr * 32 + rt * 16 + lk * 4 + r;
        obase[(size_t)row * HH + h] = acc[rt][r] + bias;
      }
  }
}

extern "C" void kernel_launch(void* const* d_in, const int* in_sizes, int n_in,
                              void* d_out, int out_size, void* d_ws, size_t ws_size,
                              hipStream_t stream) {
  const float* hidden   = (const float*)d_in[0];
  const float* router_w = (const float*)d_in[1];
  const float* router_b = (const float*)d_in[2];
  const float* w1       = (const float*)d_in[3];
  const float* b1       = (const float*)d_in[4];
  const float* w2       = (const float*)d_in[5];
  const float* b2       = (const float*)d_in[6];
  const float* counts   = (const float*)d_in[7];
  const float* drift    = (const float*)d_in[8];
  float* out            = (float*)d_out;

  float* logits = (float*)d_ws;
  int*   sel    = (int*)(logits + 256);
  float* pscale = logits + 272;
  u16*   w1p    = (u16*)((char*)d_ws + 4096);
  u16*   w2p    = (u16*)((char*)d_ws + 4096 + WBYTES);

  const size_t need = 4096 + 2 * WBYTES + 64;
  const bool useP = ws_size >= need;

  k_zero<<<1, 288, 0, stream>>>(logits);
  if (useP) k_pack<<<8192, 256, 0, stream>>>(w1, w2, w1p, w2p);
  k_pool_logits<<<512, 256, 0, stream>>>(hidden, router_w, logits);
  k_topk<<<1, 256, 0, stream>>>(logits, router_b, counts, drift, sel, pscale, out);
  if (useP)
    k_ffn2<<<256, 512, 0, stream>>>(hidden, b1, b2, w1p, w2p, sel, pscale, out);
  else
    k_ffn_fb<<<512, 512, 0, stream>>>(hidden, w1, b1, w2, b2, sel, pscale, out);
}